// Round 3
// baseline (6714.783 us; speedup 1.0000x reference)
//
#include <hip/hip_runtime.h>

#define B_ 256
#define T_ 512
#define H_ 512
#define P_ 128
#define G4 2048   // 4*H

typedef __attribute__((ext_vector_type(8))) short short8;
typedef __attribute__((ext_vector_type(8))) _Float16 h8_t;
typedef __attribute__((ext_vector_type(4))) float floatx4;

__device__ __forceinline__ float sigm(float x){ return 1.0f / (1.0f + __expf(-x)); }
__device__ __forceinline__ float tanh_(float x){ return 2.0f / (1.0f + __expf(-2.0f*x)) - 1.0f; }
__device__ __forceinline__ unsigned short f2h(float f){
  union { _Float16 h; unsigned short u; } c; c.h = (_Float16)f; return c.u;
}
__device__ __forceinline__ float wredsum(float v){
  #pragma unroll
  for (int off = 32; off; off >>= 1) v += __shfl_xor(v, off, 64);
  return v;
}

// Pack enc_Whh (2048x512 fp32 row-major [gate_col][k]) into fp16 MFMA B-frag
// order. tile = (cg*4 + w)*2 + ct; element = tile*8192 + kt*512 + lane*8 + e.
// In-tile col = q*4 + dhc (4 gates x 4 hc)  ->  Whh row = q*512 + cg*32 + w*8 + ct*4 + dhc
// k = kt*32 + (lane>>4)*8 + e
__global__ __launch_bounds__(256) void pack_w(const float* __restrict__ Whh,
                                              unsigned short* __restrict__ Wp){
  int p8   = blockIdx.x * 256 + threadIdx.x;   // 0..131071
  int lane = p8 & 63;
  int kt   = (p8 >> 6) & 15;
  int ct   = (p8 >> 10) & 1;
  int w    = (p8 >> 11) & 3;
  int cg   = (p8 >> 13) & 15;
  int q    = (lane & 15) >> 2, dhc = lane & 3;
  int col  = q*512 + cg*32 + w*8 + ct*4 + dhc;
  int k0   = kt*32 + (lane >> 4)*8;
  const float* s = Whh + (size_t)col * H_ + k0;
  unsigned short v[8];
  #pragma unroll
  for (int e = 0; e < 8; e++) v[e] = f2h(s[e]);
  *(uint4*)(Wp + (size_t)p8 * 8) = *(const uint4*)v;
}

// Persistent encoder: 256 blocks (16 batch-groups x 16 col-groups), 4 waves.
// Block (bg,cg): rows bg*16..+15, hc cg*32..+31 (all 4 gates). W in registers,
// x in LDS, c in registers, h double-buffered in global fp16.
// Per-step sync: 16-block group barrier (groups are independent).
// LDS padded >80KB so exactly 1 block/CU -> all 256 blocks co-resident.
__global__ __launch_bounds__(256) void enc_persist(
    const unsigned short* __restrict__ Wp,
    const float* __restrict__ x,
    const float* __restrict__ Wih,
    const float* __restrict__ bih,
    const float* __restrict__ bhh,
    unsigned short* __restrict__ hbuf,   // [2][256][512] fp16
    float* __restrict__ hfp,
    float* __restrict__ cfin,
    float* __restrict__ G,
    unsigned* __restrict__ cnt,
    int zero_flag)
{
  __shared__ float x_lds[16][512];      // 32 KB
  __shared__ uint4 A_lds4[1024];        // 16 KB, XOR-swizzled fp16 A tile
  __shared__ float Sg[4][16][33];       // 8448 B (pad 33: conflict-free epilogue read)
  __shared__ char pad_[30000];          // force LDS>80KB => 1 block/CU (co-residency)

  char* A_lds = (char*)A_lds4;
  const int bid = blockIdx.x;
  const int bg = bid >> 4, cg = bid & 15;
  const int tid = threadIdx.x;
  const int lane = tid & 63, wv = tid >> 6;

  if (zero_flag){ pad_[tid] = (char)Wih[tid]; if (tid == 0) A_lds[0] = pad_[128]; }

  // ---- load W fragments into registers (once): 128 VGPR/wave
  h8_t wreg[2][16];
  {
    const unsigned short* wb = Wp + (size_t)((cg*4 + wv)*2) * 8192;
    #pragma unroll
    for (int ct = 0; ct < 2; ct++)
      #pragma unroll
      for (int kt = 0; kt < 16; kt++)
        wreg[ct][kt] = *(const h8_t*)(wb + (ct*16 + kt)*512 + lane*8);
  }
  // ---- stage x rows (once)
  #pragma unroll
  for (int i = 0; i < 8; i++){
    int idx = tid + i*256;
    int r = idx >> 7, c4 = (idx & 127)*4;
    *(float4*)&x_lds[r][c4] = *(const float4*)&x[(size_t)(bg*16 + r)*T_ + c4];
  }
  // ---- epilogue constants (per thread: one hc, rows er and er+8)
  const int hc = tid & 31, er = tid >> 5;
  const int hcg = cg*32 + hc;
  float wih[4], bs[4];
  #pragma unroll
  for (int q = 0; q < 4; q++){
    wih[q] = Wih[q*512 + hcg];
    bs[q]  = bih[q*512 + hcg] + bhh[q*512 + hcg];
  }
  float cr[2] = {0.f, 0.f};

  // ---- A staging offsets (LDS dest swizzled: byte ^= (row&7)<<4)
  int ldso[4], gofs[4];
  #pragma unroll
  for (int j = 0; j < 4; j++){
    int idx16 = j*256 + tid;
    int srow = idx16 >> 6, slot = idx16 & 63;
    ldso[j] = srow*1024 + ((slot*16) ^ ((srow & 7) << 4));
    gofs[j] = (bg*16 + srow)*512 + slot*8;     // in shorts
  }
  const int arow = lane & 15, ahalf = lane >> 4;
  const int rxor = (arow & 7) << 4;
  unsigned* bar = cnt + bg*16;   // 64B-spaced per-group counters

  for (int t = 0; t <= T_; t++){
    // h(t-1) lives in buf[(t-1)&1] = buf[(t+1)&1]; zeros pre-seeded in buf[1]
    const unsigned short* hsrc = hbuf + (size_t)((t+1)&1) * 131072;
    #pragma unroll
    for (int j = 0; j < 4; j++)
      *(uint4*)(A_lds + ldso[j]) = *(const uint4*)(hsrc + gofs[j]);
    __syncthreads();

    floatx4 acc0 = {0,0,0,0}, acc1 = {0,0,0,0};
    h8_t a[16];
    #pragma unroll
    for (int kt = 0; kt < 16; kt++)
      a[kt] = *(const h8_t*)(A_lds + arow*1024 + ((kt*64 + ahalf*16) ^ rxor));
    #pragma unroll
    for (int kt = 0; kt < 16; kt++){
      acc0 = __builtin_amdgcn_mfma_f32_16x16x32_f16(a[kt], wreg[0][kt], acc0, 0,0,0);
      acc1 = __builtin_amdgcn_mfma_f32_16x16x32_f16(a[kt], wreg[1][kt], acc1, 0,0,0);
    }
    // C/D: col=lane&15 (=q*4+dhc), row=(lane>>4)*4+r
    #pragma unroll
    for (int r = 0; r < 4; r++){
      int srow = ahalf*4 + r;
      int q = (lane & 15) >> 2, dhc = lane & 3;
      Sg[q][srow][wv*8 + dhc]     = acc0[r];
      Sg[q][srow][wv*8 + 4 + dhc] = acc1[r];
    }
    __syncthreads();

    if (t == T_){   // G-phase: Gconst = h(511)@Whh^T + bsum
      #pragma unroll
      for (int e = 0; e < 2; e++){
        int row = er + e*8;
        int b = bg*16 + row;
        #pragma unroll
        for (int q = 0; q < 4; q++)
          G[(size_t)b*G4 + q*512 + hcg] = Sg[q][row][hc] + bs[q];
      }
      break;
    }

    unsigned short* hdst = hbuf + (size_t)(t&1) * 131072;
    #pragma unroll
    for (int e = 0; e < 2; e++){
      int row = er + e*8;
      float xb = x_lds[row][t];
      float pi = Sg[0][row][hc] + xb*wih[0] + bs[0];
      float pf = Sg[1][row][hc] + xb*wih[1] + bs[1];
      float pg = Sg[2][row][hc] + xb*wih[2] + bs[2];
      float po = Sg[3][row][hc] + xb*wih[3] + bs[3];
      float i_ = sigm(pi), f_ = sigm(pf), g_ = tanh_(pg), o_ = sigm(po);
      float c2 = f_*cr[e] + i_*g_;
      float h2 = o_*tanh_(c2);
      cr[e] = c2;
      int b = bg*16 + row;
      hdst[(size_t)b*512 + hcg] = f2h(h2);
      if (t == T_-1){ hfp[(size_t)b*512 + hcg] = h2; cfin[(size_t)b*512 + hcg] = c2; }
    }

    // ---- group barrier (16 blocks of this bg): release h, acquire peers' h
    __syncthreads();
    if (tid == 0){
      __hip_atomic_fetch_add(bar, 1u, __ATOMIC_RELEASE, __HIP_MEMORY_SCOPE_AGENT);
      unsigned tgt = 16u*(unsigned)(t+1);
      while (__hip_atomic_load(bar, __ATOMIC_ACQUIRE, __HIP_MEMORY_SCOPE_AGENT) < tgt)
        __builtin_amdgcn_s_sleep(1);
    }
    __syncthreads();
  }
}

// Decoder: scalar recurrence per batch row, one wave per row, zero syncs.
__global__ __launch_bounds__(256) void decoder(
    const float* __restrict__ G, const float* __restrict__ c,
    const float* __restrict__ hfp, const float* __restrict__ Wih,
    const float* __restrict__ dW, const float* __restrict__ db,
    float* __restrict__ out)
{
  const int row  = blockIdx.x * 4 + (threadIdx.x >> 6);
  const int lane = threadIdx.x & 63;
  float Gr[4][8], wr[4][8], cc[8], wd[8];
  float p = 0.f;
  #pragma unroll
  for (int k = 0; k < 8; k++){
    int j = lane + k*64;
    cc[k] = c[(size_t)row*H_ + j];
    wd[k] = dW[j];
    #pragma unroll
    for (int q = 0; q < 4; q++){
      Gr[q][k] = G[(size_t)row*G4 + q*512 + j];
      wr[q][k] = Wih[q*512 + j];
    }
    p += hfp[(size_t)row*H_ + j] * wd[k];
  }
  const float bias = db[0];
  float y = wredsum(p) + bias;
  for (int tt = 0; tt < P_; tt++){
    if (lane == 0) out[(size_t)row*P_ + tt] = y;
    if (tt == P_-1) break;
    float pp = 0.f;
    #pragma unroll
    for (int k = 0; k < 8; k++){
      float i_ = sigm (y*wr[0][k] + Gr[0][k]);
      float f_ = sigm (y*wr[1][k] + Gr[1][k]);
      float g_ = tanh_(y*wr[2][k] + Gr[2][k]);
      float o_ = sigm (y*wr[3][k] + Gr[3][k]);
      float c2 = f_*cc[k] + i_*g_;
      pp += o_*tanh_(c2)*wd[k];
    }
    y = wredsum(pp) + bias;
  }
}

extern "C" void kernel_launch(void* const* d_in, const int* in_sizes, int n_in,
                              void* d_out, int out_size, void* d_ws, size_t ws_size,
                              hipStream_t stream)
{
  const float* x    = (const float*)d_in[0];
  const float* Wih  = (const float*)d_in[1];
  const float* Whh  = (const float*)d_in[2];
  const float* bih  = (const float*)d_in[3];
  const float* bhh  = (const float*)d_in[4];
  // d_in[5..8] = dec_* : provably unused by the reference output
  const float* dW   = (const float*)d_in[9];
  const float* db   = (const float*)d_in[10];
  float* out = (float*)d_out;

  unsigned short* Wp   = (unsigned short*)d_ws;   // 1048576 u16 (2 MB)
  unsigned short* hbuf = Wp + 1048576;            // 2 x 131072 u16 (512 KB)
  float* hfp  = (float*)(hbuf + 262144);          // 131072 f32
  float* cfin = hfp + 131072;                     // 131072 f32
  float* G    = cfin + 131072;                    // 524288 f32 (2 MB)
  unsigned* cnt = (unsigned*)(G + 524288);        // 16 groups x 16 uints (1 KB)

  hipMemsetAsync(hbuf + 131072, 0, 262144, stream);   // h(-1) = 0 in buf[1]
  hipMemsetAsync(cnt, 0, 1024, stream);
  pack_w<<<512, 256, 0, stream>>>(Whh, Wp);
  enc_persist<<<256, 256, 0, stream>>>(Wp, x, Wih, bih, bhh, hbuf,
                                       hfp, cfin, G, cnt, 0);
  decoder<<<64, 256, 0, stream>>>(G, cfin, hfp, Wih, dW, db, out);
}

// Round 4
// 2883.143 us; speedup vs baseline: 2.3290x; 2.3290x over previous
//
#include <hip/hip_runtime.h>

#define B_ 256
#define T_ 512
#define H_ 512
#define P_ 128
#define G4 2048   // 4*H

typedef __attribute__((ext_vector_type(8))) _Float16 h8_t;
typedef __attribute__((ext_vector_type(4))) float floatx4;

__device__ __forceinline__ float sigm(float x){ return 1.0f / (1.0f + __expf(-x)); }
__device__ __forceinline__ float tanh_(float x){ return 2.0f / (1.0f + __expf(-2.0f*x)) - 1.0f; }
__device__ __forceinline__ unsigned short f2h(float f){
  union { _Float16 h; unsigned short u; } c; c.h = (_Float16)f; return c.u;
}
__device__ __forceinline__ float wredsum(float v){
  #pragma unroll
  for (int off = 32; off; off >>= 1) v += __shfl_xor(v, off, 64);
  return v;
}

// Pack enc_Whh (2048x512 fp32 row-major [gate_col][k]) into fp16 MFMA B-frag
// order. tile = (cg*4 + w)*2 + ct; element = tile*8192 + kt*512 + lane*8 + e.
// In-tile col = q*4 + dhc  ->  Whh row = q*512 + cg*32 + w*8 + ct*4 + dhc
// k = kt*32 + (lane>>4)*8 + e
__global__ __launch_bounds__(256) void pack_w(const float* __restrict__ Whh,
                                              unsigned short* __restrict__ Wp){
  int p8   = blockIdx.x * 256 + threadIdx.x;   // 0..131071
  int lane = p8 & 63;
  int kt   = (p8 >> 6) & 15;
  int ct   = (p8 >> 10) & 1;
  int w    = (p8 >> 11) & 3;
  int cg   = (p8 >> 13) & 15;
  int q    = (lane & 15) >> 2, dhc = lane & 3;
  int col  = q*512 + cg*32 + w*8 + ct*4 + dhc;
  int k0   = kt*32 + (lane >> 4)*8;
  const float* s = Whh + (size_t)col * H_ + k0;
  unsigned short v[8];
  #pragma unroll
  for (int e = 0; e < 8; e++) v[e] = f2h(s[e]);
  *(uint4*)(Wp + (size_t)p8 * 8) = *(const uint4*)v;
}

// Persistent encoder: 256 blocks (16 batch-groups x 16 col-groups), 4 waves.
// h exchange: self-tagging u64 words {tag | 2 x fp16} via relaxed agent
// atomics (IF$-coherent, NO fences, NO barrier, NO L2 writeback/invalidate).
// Double-buffered X => producer at most 1 step ahead of any consumer => safe.
__global__ __launch_bounds__(256) void enc_persist(
    const unsigned short* __restrict__ Wp,
    const float* __restrict__ x,
    const float* __restrict__ Wih,
    const float* __restrict__ bih,
    const float* __restrict__ bhh,
    unsigned long long* __restrict__ X,   // [2][256 rows][256 colpairs] u64
    float* __restrict__ hfp,
    float* __restrict__ cfin,
    float* __restrict__ G,
    int zf)
{
  __shared__ float x_lds[16][512];      // 32 KB
  __shared__ uint4 A_lds4[1024];        // 16 KB, XOR-swizzled fp16 A tile
  __shared__ float Sg[4][16][33];       // 8448 B
  __shared__ char pad_[30000];          // force LDS>80KB => 1 block/CU

  char* A_lds = (char*)A_lds4;
  const int bid = blockIdx.x;
  const int bg = bid >> 4, cg = bid & 15;
  const int tid = threadIdx.x;
  const int lane = tid & 63, wv = tid >> 6;

  if (zf){ pad_[tid] = (char)Wih[tid]; if (!tid) A_lds[0] = pad_[128]; }

  // ---- W fragments into registers (once): 128 regs/wave
  h8_t wreg[2][16];
  {
    const unsigned short* wb = Wp + (size_t)((cg*4 + wv)*2) * 8192;
    #pragma unroll
    for (int ct = 0; ct < 2; ct++)
      #pragma unroll
      for (int kt = 0; kt < 16; kt++)
        wreg[ct][kt] = *(const h8_t*)(wb + (ct*16 + kt)*512 + lane*8);
  }
  // ---- stage x rows (once)
  #pragma unroll
  for (int i = 0; i < 8; i++){
    int idx = tid + i*256;
    int r = idx >> 7, c4 = (idx & 127)*4;
    *(float4*)&x_lds[r][c4] = *(const float4*)&x[(size_t)(bg*16 + r)*T_ + c4];
  }
  // ---- per-thread epilogue: one row, two adjacent hc
  const int erow = tid >> 4;            // 0..15
  const int hp   = tid & 15;            // col-pair within block
  const int hc0  = cg*32 + hp*2;
  float wih0[4], wih1[4], bs0[4], bs1[4];
  #pragma unroll
  for (int q = 0; q < 4; q++){
    wih0[q] = Wih[q*512 + hc0];     wih1[q] = Wih[q*512 + hc0 + 1];
    bs0[q]  = bih[q*512 + hc0]     + bhh[q*512 + hc0];
    bs1[q]  = bih[q*512 + hc0 + 1] + bhh[q*512 + hc0 + 1];
  }
  float cr0 = 0.f, cr1 = 0.f;

  // ---- staging: thread loads row erow, colpairs hp + j*16 (j=0..15)
  const size_t Xrow = (size_t)(bg*16 + erow)*256 + hp;
  int lws[16];
  #pragma unroll
  for (int j = 0; j < 16; j++){
    int cp = hp + j*16;
    lws[j] = erow*1024 + ((cp*4) ^ ((erow & 7) << 4));
  }
  const int arow = lane & 15, ahalf = lane >> 4;
  const int rxor = (arow & 7) << 4;
  const size_t pidx = (size_t)(bg*16 + erow)*256 + cg*16 + hp;

  for (int t = 0; t <= T_; t++){
    // ---- acquire h(t-1): tagged words, buffer (t+1)&1, tag == t
    unsigned long long* Xb = X + (size_t)((t+1)&1) * 65536;
    const unsigned wtag = (unsigned)t;
    unsigned long long w[16];
    #pragma unroll
    for (int j = 0; j < 16; j++)
      w[j] = __hip_atomic_load(Xb + Xrow + j*16, __ATOMIC_RELAXED,
                               __HIP_MEMORY_SCOPE_AGENT);
    #pragma unroll
    for (int j = 0; j < 16; j++){
      while ((unsigned)(w[j] >> 32) != wtag)
        w[j] = __hip_atomic_load(Xb + Xrow + j*16, __ATOMIC_RELAXED,
                                 __HIP_MEMORY_SCOPE_AGENT);
    }
    #pragma unroll
    for (int j = 0; j < 16; j++)
      *(unsigned*)(A_lds + lws[j]) = (unsigned)w[j];
    __syncthreads();

    floatx4 acc0 = {0,0,0,0}, acc1 = {0,0,0,0};
    h8_t a[16];
    #pragma unroll
    for (int kt = 0; kt < 16; kt++)
      a[kt] = *(const h8_t*)(A_lds + arow*1024 + ((kt*64 + ahalf*16) ^ rxor));
    #pragma unroll
    for (int kt = 0; kt < 16; kt++){
      acc0 = __builtin_amdgcn_mfma_f32_16x16x32_f16(a[kt], wreg[0][kt], acc0, 0,0,0);
      acc1 = __builtin_amdgcn_mfma_f32_16x16x32_f16(a[kt], wreg[1][kt], acc1, 0,0,0);
    }
    // C/D: col=lane&15 (=q*4+dhc), row=(lane>>4)*4+r
    #pragma unroll
    for (int r = 0; r < 4; r++){
      int srow = ahalf*4 + r;
      int q = (lane & 15) >> 2, dhc = lane & 3;
      Sg[q][srow][wv*8 + dhc]     = acc0[r];
      Sg[q][srow][wv*8 + 4 + dhc] = acc1[r];
    }
    __syncthreads();

    if (t == T_){   // Gconst = h(511)@Whh^T + bsum
      int b = bg*16 + erow;
      #pragma unroll
      for (int q = 0; q < 4; q++){
        G[(size_t)b*G4 + q*512 + hc0]     = Sg[q][erow][hp*2]     + bs0[q];
        G[(size_t)b*G4 + q*512 + hc0 + 1] = Sg[q][erow][hp*2 + 1] + bs1[q];
      }
      break;
    }

    const float xb = x_lds[erow][t];
    float pi0 = Sg[0][erow][hp*2] + xb*wih0[0] + bs0[0];
    float pf0 = Sg[1][erow][hp*2] + xb*wih0[1] + bs0[1];
    float pg0 = Sg[2][erow][hp*2] + xb*wih0[2] + bs0[2];
    float po0 = Sg[3][erow][hp*2] + xb*wih0[3] + bs0[3];
    float c20 = sigm(pf0)*cr0 + sigm(pi0)*tanh_(pg0);
    float h0  = sigm(po0)*tanh_(c20);  cr0 = c20;

    float pi1 = Sg[0][erow][hp*2+1] + xb*wih1[0] + bs1[0];
    float pf1 = Sg[1][erow][hp*2+1] + xb*wih1[1] + bs1[1];
    float pg1 = Sg[2][erow][hp*2+1] + xb*wih1[2] + bs1[2];
    float po1 = Sg[3][erow][hp*2+1] + xb*wih1[3] + bs1[3];
    float c21 = sigm(pf1)*cr1 + sigm(pi1)*tanh_(pg1);
    float h1  = sigm(po1)*tanh_(c21);  cr1 = c21;

    if (t == T_-1){
      int b = bg*16 + erow;
      hfp[(size_t)b*512 + hc0]     = h0;  hfp[(size_t)b*512 + hc0 + 1] = h1;
      cfin[(size_t)b*512 + hc0]    = c20; cfin[(size_t)b*512 + hc0 + 1] = c21;
    }
    unsigned pay = (unsigned)f2h(h0) | ((unsigned)f2h(h1) << 16);
    unsigned long long wo = ((unsigned long long)(t + 1) << 32) | pay;
    __hip_atomic_store(X + (size_t)(t & 1)*65536 + pidx, wo,
                       __ATOMIC_RELAXED, __HIP_MEMORY_SCOPE_AGENT);
    // no trailing barrier: next-iter A_lds writes are fenced by sync #1,
    // and everyone past sync #2 has finished this iter's A/Sg reads.
  }
}

// Decoder: scalar recurrence per batch row, one wave per row, zero syncs.
__global__ __launch_bounds__(256) void decoder(
    const float* __restrict__ G, const float* __restrict__ c,
    const float* __restrict__ hfp, const float* __restrict__ Wih,
    const float* __restrict__ dW, const float* __restrict__ db,
    float* __restrict__ out)
{
  const int row  = blockIdx.x * 4 + (threadIdx.x >> 6);
  const int lane = threadIdx.x & 63;
  float Gr[4][8], wr[4][8], cc[8], wd[8];
  float p = 0.f;
  #pragma unroll
  for (int k = 0; k < 8; k++){
    int j = lane + k*64;
    cc[k] = c[(size_t)row*H_ + j];
    wd[k] = dW[j];
    #pragma unroll
    for (int q = 0; q < 4; q++){
      Gr[q][k] = G[(size_t)row*G4 + q*512 + j];
      wr[q][k] = Wih[q*512 + j];
    }
    p += hfp[(size_t)row*H_ + j] * wd[k];
  }
  const float bias = db[0];
  float y = wredsum(p) + bias;
  for (int tt = 0; tt < P_; tt++){
    if (lane == 0) out[(size_t)row*P_ + tt] = y;
    if (tt == P_-1) break;
    float pp = 0.f;
    #pragma unroll
    for (int k = 0; k < 8; k++){
      float i_ = sigm (y*wr[0][k] + Gr[0][k]);
      float f_ = sigm (y*wr[1][k] + Gr[1][k]);
      float g_ = tanh_(y*wr[2][k] + Gr[2][k]);
      float o_ = sigm (y*wr[3][k] + Gr[3][k]);
      float c2 = f_*cc[k] + i_*g_;
      pp += o_*tanh_(c2)*wd[k];
    }
    y = wredsum(pp) + bias;
  }
}

extern "C" void kernel_launch(void* const* d_in, const int* in_sizes, int n_in,
                              void* d_out, int out_size, void* d_ws, size_t ws_size,
                              hipStream_t stream)
{
  const float* x    = (const float*)d_in[0];
  const float* Wih  = (const float*)d_in[1];
  const float* Whh  = (const float*)d_in[2];
  const float* bih  = (const float*)d_in[3];
  const float* bhh  = (const float*)d_in[4];
  // d_in[5..8] = dec_* : provably unused by the reference output
  const float* dW   = (const float*)d_in[9];
  const float* db   = (const float*)d_in[10];
  float* out = (float*)d_out;

  unsigned short* Wp    = (unsigned short*)d_ws;            // 2 MB
  unsigned long long* X = (unsigned long long*)(Wp + 1048576); // 131072 u64 (1 MB)
  float* hfp  = (float*)(X + 131072);                       // 131072 f32
  float* cfin = hfp + 131072;                               // 131072 f32
  float* G    = cfin + 131072;                              // 524288 f32 (2 MB)

  // buffer 1 = h(-1): tag 0, payload 0
  hipMemsetAsync(X + 65536, 0, 65536 * sizeof(unsigned long long), stream);
  pack_w<<<512, 256, 0, stream>>>(Whh, Wp);
  enc_persist<<<256, 256, 0, stream>>>(Wp, x, Wih, bih, bhh, X,
                                       hfp, cfin, G, 0);
  decoder<<<64, 256, 0, stream>>>(G, cfin, hfp, Wih, dW, db, out);
}

// Round 5
// 1936.290 us; speedup vs baseline: 3.4679x; 1.4890x over previous
//
#include <hip/hip_runtime.h>

#define B_ 256
#define T_ 512
#define H_ 512
#define P_ 128
#define G4 2048   // 4*H

typedef __attribute__((ext_vector_type(8))) _Float16 h8_t;
typedef __attribute__((ext_vector_type(4))) float floatx4;

__device__ __forceinline__ float sigm(float x){ return 1.0f / (1.0f + __expf(-x)); }
__device__ __forceinline__ float tanh_(float x){ return 2.0f / (1.0f + __expf(-2.0f*x)) - 1.0f; }
__device__ __forceinline__ unsigned short f2h(float f){
  union { _Float16 h; unsigned short u; } c; c.h = (_Float16)f; return c.u;
}
__device__ __forceinline__ float wredsum(float v){
  #pragma unroll
  for (int off = 32; off; off >>= 1) v += __shfl_xor(v, off, 64);
  return v;
}

// Pack enc_Whh (2048x512 fp32 row-major [gate_col][k]) into fp16 MFMA B-frag
// order. tile = (cg*4 + w)*2 + ct; element = tile*8192 + kt*512 + lane*8 + e.
// In-tile col = q*4 + dhc  ->  Whh row = q*512 + cg*32 + w*8 + ct*4 + dhc
// k = kt*32 + (lane>>4)*8 + e
__global__ __launch_bounds__(256) void pack_w(const float* __restrict__ Whh,
                                              unsigned short* __restrict__ Wp){
  int p8   = blockIdx.x * 256 + threadIdx.x;   // 0..131071
  int lane = p8 & 63;
  int kt   = (p8 >> 6) & 15;
  int ct   = (p8 >> 10) & 1;
  int w    = (p8 >> 11) & 3;
  int cg   = (p8 >> 13) & 15;
  int q    = (lane & 15) >> 2, dhc = lane & 3;
  int col  = q*512 + cg*32 + w*8 + ct*4 + dhc;
  int k0   = kt*32 + (lane >> 4)*8;
  const float* s = Whh + (size_t)col * H_ + k0;
  unsigned short v[8];
  #pragma unroll
  for (int e = 0; e < 8; e++) v[e] = f2h(s[e]);
  *(uint4*)(Wp + (size_t)p8 * 8) = *(const uint4*)v;
}

// Persistent encoder: 256 blocks (16 batch-groups x 16 col-groups), 4 waves.
// h exchange: self-tagging u64 words {tag | 2 x fp16}. Producer uses agent
// atomic EXCHANGE (RMW executes at coherence point -> immediately visible,
// no dirty-L2 eviction wait). Consumer: parallel-retry poll, one vmcnt wait
// per round, stage-to-LDS on match, s_sleep backoff.
__global__ __launch_bounds__(256) void enc_persist(
    const unsigned short* __restrict__ Wp,
    const float* __restrict__ x,
    const float* __restrict__ Wih,
    const float* __restrict__ bih,
    const float* __restrict__ bhh,
    unsigned long long* __restrict__ X,   // [2][256 rows][256 colpairs] u64
    float* __restrict__ hfp,
    float* __restrict__ cfin,
    float* __restrict__ G,
    int zf)
{
  __shared__ float x_lds[16][512];      // 32 KB
  __shared__ uint4 A_lds4[1024];        // 16 KB, XOR-swizzled fp16 A tile
  __shared__ float Sg[4][16][33];       // 8448 B
  __shared__ char pad_[30000];          // force LDS>80KB => 1 block/CU

  char* A_lds = (char*)A_lds4;
  const int bid = blockIdx.x;
  const int bg = bid >> 4, cg = bid & 15;
  const int tid = threadIdx.x;
  const int lane = tid & 63, wv = tid >> 6;

  if (zf){ pad_[tid] = (char)Wih[tid]; if (!tid) A_lds[0] = pad_[128]; }

  // ---- W fragments into registers (once): 128 regs/wave
  h8_t wreg[2][16];
  {
    const unsigned short* wb = Wp + (size_t)((cg*4 + wv)*2) * 8192;
    #pragma unroll
    for (int ct = 0; ct < 2; ct++)
      #pragma unroll
      for (int kt = 0; kt < 16; kt++)
        wreg[ct][kt] = *(const h8_t*)(wb + (ct*16 + kt)*512 + lane*8);
  }
  // ---- stage x rows (once)
  #pragma unroll
  for (int i = 0; i < 8; i++){
    int idx = tid + i*256;
    int r = idx >> 7, c4 = (idx & 127)*4;
    *(float4*)&x_lds[r][c4] = *(const float4*)&x[(size_t)(bg*16 + r)*T_ + c4];
  }
  // ---- per-thread epilogue: one row, two adjacent hc
  const int erow = tid >> 4;            // 0..15
  const int hp   = tid & 15;            // col-pair within block
  const int hc0  = cg*32 + hp*2;
  float wih0[4], wih1[4], bs0[4], bs1[4];
  #pragma unroll
  for (int q = 0; q < 4; q++){
    wih0[q] = Wih[q*512 + hc0];     wih1[q] = Wih[q*512 + hc0 + 1];
    bs0[q]  = bih[q*512 + hc0]     + bhh[q*512 + hc0];
    bs1[q]  = bih[q*512 + hc0 + 1] + bhh[q*512 + hc0 + 1];
  }
  float cr0 = 0.f, cr1 = 0.f;

  // ---- staging: thread owns row erow, colpairs hp + j*16 (j = producer cg')
  const size_t Xrow = (size_t)(bg*16 + erow)*256 + hp;
  int lws[16];
  #pragma unroll
  for (int j = 0; j < 16; j++){
    int cp = hp + j*16;
    lws[j] = erow*1024 + ((cp*4) ^ ((erow & 7) << 4));
  }
  const int arow = lane & 15, ahalf = lane >> 4;
  const int rxor = (arow & 7) << 4;
  const size_t pidx = (size_t)(bg*16 + erow)*256 + cg*16 + hp;

  for (int t = 0; t <= T_; t++){
    // ---- acquire h(t-1): tagged words, buffer (t+1)&1, tag == t
    unsigned long long* Xb = X + (size_t)((t+1)&1) * 65536;
    const unsigned wtag = (unsigned)t;
    unsigned pend = 0xFFFFu;
    do {
      unsigned long long tmp[16];
      #pragma unroll
      for (int j = 0; j < 16; j++)
        if (pend & (1u << j))
          tmp[j] = __hip_atomic_load(Xb + Xrow + j*16, __ATOMIC_RELAXED,
                                     __HIP_MEMORY_SCOPE_AGENT);
      unsigned np = 0u;
      #pragma unroll
      for (int j = 0; j < 16; j++){
        if (pend & (1u << j)){
          if ((unsigned)(tmp[j] >> 32) == wtag)
            *(unsigned*)(A_lds + lws[j]) = (unsigned)tmp[j];
          else
            np |= 1u << j;
        }
      }
      pend = np;
      if (pend) __builtin_amdgcn_s_sleep(1);
    } while (pend);
    __syncthreads();

    floatx4 acc0 = {0,0,0,0}, acc1 = {0,0,0,0};
    h8_t a[16];
    #pragma unroll
    for (int kt = 0; kt < 16; kt++)
      a[kt] = *(const h8_t*)(A_lds + arow*1024 + ((kt*64 + ahalf*16) ^ rxor));
    #pragma unroll
    for (int kt = 0; kt < 16; kt++){
      acc0 = __builtin_amdgcn_mfma_f32_16x16x32_f16(a[kt], wreg[0][kt], acc0, 0,0,0);
      acc1 = __builtin_amdgcn_mfma_f32_16x16x32_f16(a[kt], wreg[1][kt], acc1, 0,0,0);
    }
    // C/D: col=lane&15 (=q*4+dhc), row=(lane>>4)*4+r
    #pragma unroll
    for (int r = 0; r < 4; r++){
      int srow = ahalf*4 + r;
      int q = (lane & 15) >> 2, dhc = lane & 3;
      Sg[q][srow][wv*8 + dhc]     = acc0[r];
      Sg[q][srow][wv*8 + 4 + dhc] = acc1[r];
    }
    __syncthreads();

    if (t == T_){   // Gconst = h(511)@Whh^T + bsum
      int b = bg*16 + erow;
      #pragma unroll
      for (int q = 0; q < 4; q++){
        G[(size_t)b*G4 + q*512 + hc0]     = Sg[q][erow][hp*2]     + bs0[q];
        G[(size_t)b*G4 + q*512 + hc0 + 1] = Sg[q][erow][hp*2 + 1] + bs1[q];
      }
      break;
    }

    const float xb = x_lds[erow][t];
    float pi0 = Sg[0][erow][hp*2] + xb*wih0[0] + bs0[0];
    float pf0 = Sg[1][erow][hp*2] + xb*wih0[1] + bs0[1];
    float pg0 = Sg[2][erow][hp*2] + xb*wih0[2] + bs0[2];
    float po0 = Sg[3][erow][hp*2] + xb*wih0[3] + bs0[3];
    float c20 = sigm(pf0)*cr0 + sigm(pi0)*tanh_(pg0);
    float h0  = sigm(po0)*tanh_(c20);  cr0 = c20;

    float pi1 = Sg[0][erow][hp*2+1] + xb*wih1[0] + bs1[0];
    float pf1 = Sg[1][erow][hp*2+1] + xb*wih1[1] + bs1[1];
    float pg1 = Sg[2][erow][hp*2+1] + xb*wih1[2] + bs1[2];
    float po1 = Sg[3][erow][hp*2+1] + xb*wih1[3] + bs1[3];
    float c21 = sigm(pf1)*cr1 + sigm(pi1)*tanh_(c21*0.f + pg1*0.f + pg1); // keep simple
    // (note: expression simplified below)
    c21 = sigm(pf1)*cr1 + sigm(pi1)*tanh_(pg1);
    float h1  = sigm(po1)*tanh_(c21);  cr1 = c21;

    if (t == T_-1){
      int b = bg*16 + erow;
      hfp[(size_t)b*512 + hc0]     = h0;  hfp[(size_t)b*512 + hc0 + 1] = h1;
      cfin[(size_t)b*512 + hc0]    = c20; cfin[(size_t)b*512 + hc0 + 1] = c21;
    }
    unsigned pay = (unsigned)f2h(h0) | ((unsigned)f2h(h1) << 16);
    unsigned long long wo = ((unsigned long long)(t + 1) << 32) | pay;
    (void)__hip_atomic_exchange(X + (size_t)(t & 1)*65536 + pidx, wo,
                                __ATOMIC_RELAXED, __HIP_MEMORY_SCOPE_AGENT);
  }
}

// Decoder: scalar recurrence per batch row, one wave per row, zero syncs.
__global__ __launch_bounds__(256) void decoder(
    const float* __restrict__ G, const float* __restrict__ c,
    const float* __restrict__ hfp, const float* __restrict__ Wih,
    const float* __restrict__ dW, const float* __restrict__ db,
    float* __restrict__ out)
{
  const int row  = blockIdx.x * 4 + (threadIdx.x >> 6);
  const int lane = threadIdx.x & 63;
  float Gr[4][8], wr[4][8], cc[8], wd[8];
  float p = 0.f;
  #pragma unroll
  for (int k = 0; k < 8; k++){
    int j = lane + k*64;
    cc[k] = c[(size_t)row*H_ + j];
    wd[k] = dW[j];
    #pragma unroll
    for (int q = 0; q < 4; q++){
      Gr[q][k] = G[(size_t)row*G4 + q*512 + j];
      wr[q][k] = Wih[q*512 + j];
    }
    p += hfp[(size_t)row*H_ + j] * wd[k];
  }
  const float bias = db[0];
  float y = wredsum(p) + bias;
  for (int tt = 0; tt < P_; tt++){
    if (lane == 0) out[(size_t)row*P_ + tt] = y;
    if (tt == P_-1) break;
    float pp = 0.f;
    #pragma unroll
    for (int k = 0; k < 8; k++){
      float i_ = sigm (y*wr[0][k] + Gr[0][k]);
      float f_ = sigm (y*wr[1][k] + Gr[1][k]);
      float g_ = tanh_(y*wr[2][k] + Gr[2][k]);
      float o_ = sigm (y*wr[3][k] + Gr[3][k]);
      float c2 = f_*cc[k] + i_*g_;
      pp += o_*tanh_(c2)*wd[k];
    }
    y = wredsum(pp) + bias;
  }
}

extern "C" void kernel_launch(void* const* d_in, const int* in_sizes, int n_in,
                              void* d_out, int out_size, void* d_ws, size_t ws_size,
                              hipStream_t stream)
{
  const float* x    = (const float*)d_in[0];
  const float* Wih  = (const float*)d_in[1];
  const float* Whh  = (const float*)d_in[2];
  const float* bih  = (const float*)d_in[3];
  const float* bhh  = (const float*)d_in[4];
  // d_in[5..8] = dec_* : provably unused by the reference output
  const float* dW   = (const float*)d_in[9];
  const float* db   = (const float*)d_in[10];
  float* out = (float*)d_out;

  unsigned short* Wp    = (unsigned short*)d_ws;            // 2 MB
  unsigned long long* X = (unsigned long long*)(Wp + 1048576); // 131072 u64 (1 MB)
  float* hfp  = (float*)(X + 131072);                       // 131072 f32
  float* cfin = hfp + 131072;                               // 131072 f32
  float* G    = cfin + 131072;                              // 524288 f32 (2 MB)

  // buffer 1 = h(-1): tag 0, payload 0
  hipMemsetAsync(X + 65536, 0, 65536 * sizeof(unsigned long long), stream);
  pack_w<<<512, 256, 0, stream>>>(Whh, Wp);
  enc_persist<<<256, 256, 0, stream>>>(Wp, x, Wih, bih, bhh, X,
                                       hfp, cfin, G, 0);
  decoder<<<64, 256, 0, stream>>>(G, cfin, hfp, Wih, dW, db, out);
}